// Round 1
// baseline (242.539 us; speedup 1.0000x reference)
//
#include <hip/hip_runtime.h>
#include <hip/hip_bf16.h>
#include <stdint.h>

// ---------------------------------------------------------------------------
// BinaryMLP: out = (relu(relu(relu(x@B(w1)^T+b1)@B(w2)^T+b2)@B(w3)^T+b3))@w4^T+b4
// B(w) = sign(w) in {-1,+1}  (exact in bf16)
// x: 65536x784 f32, w1:512x784, w2,w3:512x512, w4:10x512, out: 65536x10 f32
//
// Plan: prep kernel binarizes/converts weights into d_ws, laid out per-K-tile
// pre-swizzled (XOR bank swizzle baked into the GLOBAL layout so that a linear
// global_load_lds copy produces the swizzled LDS image). Fused main kernel:
// one block = 128 batch rows through all 4 layers; activations live in LDS.
// ---------------------------------------------------------------------------

typedef __attribute__((ext_vector_type(8))) short short8;   // 8 bf16 (4 VGPRs)
typedef __attribute__((ext_vector_type(4))) float f32x4;    // MFMA accum

#define THREADS 512
#define BM      128
#define HID     512
#define K1      784
#define K1P     800
#define BK      32
#define NK1     (K1P / BK)      // 25
#define NK2     (HID / BK)      // 16
#define WCHUNK  (HID * BK * 2)  // 32768 B per K-tile of a 512-col weight panel

#define W1_OFF  0
#define W1_BYTES (NK1 * WCHUNK)             // 819200
#define W2_OFF  (W1_OFF + W1_BYTES)
#define W2_BYTES (NK2 * WCHUNK)             // 524288
#define W3_OFF  (W2_OFF + W2_BYTES)
#define W4_OFF  (W3_OFF + W2_BYTES)
#define W4_BYTES (16 * HID * 2)             // 16384 (rows 10..15 zero)
#define WS_BYTES (W4_OFF + W4_BYTES)        // 1884160

#define LDS_W   (BM * HID * 2)              // H region: [0, 131072)
#define LDS_TOTAL (LDS_W + WCHUNK)          // 163840 = 160 KiB

// round-to-nearest-even f32 -> bf16 (bit trick; NaN irrelevant here)
__device__ __forceinline__ unsigned short f2bf(float f) {
    union { float f; unsigned u; } v; v.f = f;
    unsigned r = v.u + 0x7FFFu + ((v.u >> 16) & 1u);
    return (unsigned short)(r >> 16);
}

// ---------------------------------------------------------------------------
// prep: write binarized/converted weights into ws, per-K-tile chunks,
// pre-swizzled: within a chunk, element (n, kk) lives at byte
//   (n*64 + kk*2) ^ ((n&7)<<4)          [row stride 64 B  = BK bf16]
// w4 panel (16x512, row stride 1024 B): (n*1024 + k*2) ^ ((n&7)<<4)
// ---------------------------------------------------------------------------
__global__ void prep_weights(const float* __restrict__ w1, const float* __restrict__ w2,
                             const float* __restrict__ w3, const float* __restrict__ w4,
                             unsigned char* __restrict__ ws)
{
    int id = blockIdx.x * blockDim.x + threadIdx.x;
    const int N1 = HID * K1P;       // 409600
    const int N2 = HID * HID;       // 262144
    const int N4 = 16 * HID;        // 8192

    if (id < N1) {
        int n = id / K1P, kp = id % K1P;
        unsigned short v = 0;
        if (kp < K1) v = (w1[n * K1 + kp] >= 0.0f) ? 0x3F80u : 0xBF80u;
        unsigned off = W1_OFF + (kp >> 5) * WCHUNK
                     + (((unsigned)(n * 64 + (kp & 31) * 2)) ^ (unsigned)((n & 7) << 4));
        *(unsigned short*)(ws + off) = v;
        return;
    }
    id -= N1;
    if (id < N2) {
        int n = id / HID, k = id % HID;
        unsigned short v = (w2[n * HID + k] >= 0.0f) ? 0x3F80u : 0xBF80u;
        unsigned off = W2_OFF + (k >> 5) * WCHUNK
                     + (((unsigned)(n * 64 + (k & 31) * 2)) ^ (unsigned)((n & 7) << 4));
        *(unsigned short*)(ws + off) = v;
        return;
    }
    id -= N2;
    if (id < N2) {
        int n = id / HID, k = id % HID;
        unsigned short v = (w3[n * HID + k] >= 0.0f) ? 0x3F80u : 0xBF80u;
        unsigned off = W3_OFF + (k >> 5) * WCHUNK
                     + (((unsigned)(n * 64 + (k & 31) * 2)) ^ (unsigned)((n & 7) << 4));
        *(unsigned short*)(ws + off) = v;
        return;
    }
    id -= N2;
    if (id < N4) {
        int n = id / HID, k = id % HID;
        unsigned short v = (n < 10) ? f2bf(w4[n * HID + k]) : 0;
        unsigned off = W4_OFF + (((unsigned)(n * 1024 + k * 2)) ^ (unsigned)((n & 7) << 4));
        *(unsigned short*)(ws + off) = v;
    }
}

// ---------------------------------------------------------------------------
// fused MLP: 1 block = 128 batch rows, 8 waves (2 M x 4 N), mfma 16x16x32 bf16
// ---------------------------------------------------------------------------
__global__ __launch_bounds__(THREADS, 2)
void fused_mlp(const float* __restrict__ x,
               const unsigned char* __restrict__ ws,
               const float* __restrict__ b1, const float* __restrict__ b2,
               const float* __restrict__ b3, const float* __restrict__ b4,
               float* __restrict__ out)
{
    extern __shared__ unsigned char lds[];
    const int tid  = threadIdx.x;
    const int lane = tid & 63;
    const int wave = tid >> 6;
    const int wm   = wave >> 2;          // 0..1  (64 rows each)
    const int wn   = wave & 3;           // 0..3  (128 cols each)
    const int lr   = lane & 15;          // frag row/col
    const int lg   = lane >> 4;          // k-group (8 bf16 each)
    const int row_base = blockIdx.x * BM;

    // stage one 512xBK weight tile (32 KiB) from pre-swizzled global chunk
    auto stageW = [&](const unsigned char* gchunk) {
        const unsigned char* src = gchunk + wave * 4096 + lane * 16;
        unsigned char* dst = lds + LDS_W + wave * 4096;
#pragma unroll
        for (int i = 0; i < 4; ++i) {
            __builtin_amdgcn_global_load_lds(
                (const __attribute__((address_space(1))) void*)(src + i * 1024),
                (__attribute__((address_space(3))) void*)(dst + i * 1024),
                16, 0, 0);
        }
    };

    // epilogue: acc -> relu(acc + bias) -> bf16 into H region (in-place safe
    // because callers barrier before/after)
    auto epilogueToH = [&](f32x4 (&acc)[4][8], const float* __restrict__ bias) {
#pragma unroll
        for (int nf = 0; nf < 8; ++nf) {
            int col = wn * 128 + nf * 16 + lr;
            float bv = bias[col];
#pragma unroll
            for (int mf = 0; mf < 4; ++mf) {
#pragma unroll
                for (int r = 0; r < 4; ++r) {
                    int row = wm * 64 + mf * 16 + lg * 4 + r;
                    float v = acc[mf][nf][r] + bv;
                    v = v > 0.0f ? v : 0.0f;
                    unsigned off = ((unsigned)(row * 1024 + col * 2)) ^ (unsigned)((row & 7) << 4);
                    *(unsigned short*)(lds + off) = f2bf(v);
                }
            }
        }
    };

    // ---------------- Layer 1: x(f32, K=784 pad 800) -> h1 ----------------
    {
        f32x4 acc[4][8];
#pragma unroll
        for (int mf = 0; mf < 4; ++mf)
#pragma unroll
            for (int nf = 0; nf < 8; ++nf)
                acc[mf][nf] = (f32x4){0.f, 0.f, 0.f, 0.f};

        for (int kt = 0; kt < NK1; ++kt) {
            __syncthreads();                       // prev iter LDS reads done
            stageW(ws + W1_OFF + kt * WCHUNK);
            // x tile: 128 rows x 32 cols f32 -> bf16 -> LDS [m][kk], stride 64B
            float4 xv[2];
#pragma unroll
            for (int i = 0; i < 2; ++i) {
                int u = tid + i * THREADS;
                int m = u >> 3, q = u & 7;
                int col = kt * BK + q * 4;
                if (col < K1)
                    xv[i] = *(const float4*)(x + (size_t)(row_base + m) * K1 + col);
                else
                    xv[i] = make_float4(0.f, 0.f, 0.f, 0.f);
            }
#pragma unroll
            for (int i = 0; i < 2; ++i) {
                int u = tid + i * THREADS;
                int m = u >> 3, q = u & 7;
                uint2 pk;
                pk.x = (unsigned)f2bf(xv[i].x) | ((unsigned)f2bf(xv[i].y) << 16);
                pk.y = (unsigned)f2bf(xv[i].z) | ((unsigned)f2bf(xv[i].w) << 16);
                unsigned off = ((unsigned)(m * 64 + q * 8)) ^ (unsigned)((m & 7) << 4);
                *(uint2*)(lds + off) = pk;
            }
            __syncthreads();                       // drains vmcnt (W) + lgkm (x)

            short8 a[4], b[8];
#pragma unroll
            for (int mf = 0; mf < 4; ++mf) {
                int m = wm * 64 + mf * 16 + lr;
                a[mf] = *(const short8*)(lds + (((unsigned)(m * 64 + lg * 16)) ^ (unsigned)((m & 7) << 4)));
            }
#pragma unroll
            for (int nf = 0; nf < 8; ++nf) {
                int n = wn * 128 + nf * 16 + lr;
                b[nf] = *(const short8*)(lds + LDS_W + (((unsigned)(n * 64 + lg * 16)) ^ (unsigned)((n & 7) << 4)));
            }
#pragma unroll
            for (int mf = 0; mf < 4; ++mf)
#pragma unroll
                for (int nf = 0; nf < 8; ++nf)
                    acc[mf][nf] = __builtin_amdgcn_mfma_f32_16x16x32_bf16(a[mf], b[nf], acc[mf][nf], 0, 0, 0);
        }
        __syncthreads();           // last-iter LDS reads done (x region == H!)
        epilogueToH(acc, b1);
        __syncthreads();           // h1 visible
    }

    // ---------------- Layers 2 & 3: h(LDS) -> h, K=512 ----------------
    for (int layer = 0; layer < 2; ++layer) {
        const unsigned char* wb = ws + (layer == 0 ? W2_OFF : W3_OFF);
        const float* bias = (layer == 0) ? b2 : b3;

        f32x4 acc[4][8];
#pragma unroll
        for (int mf = 0; mf < 4; ++mf)
#pragma unroll
            for (int nf = 0; nf < 8; ++nf)
                acc[mf][nf] = (f32x4){0.f, 0.f, 0.f, 0.f};

        for (int kt = 0; kt < NK2; ++kt) {
            __syncthreads();                       // prev iter W reads done
            stageW(wb + kt * WCHUNK);
            __syncthreads();                       // W tile ready

            short8 a[4], b[8];
#pragma unroll
            for (int mf = 0; mf < 4; ++mf) {
                int m = wm * 64 + mf * 16 + lr;
                unsigned off = ((unsigned)(m * 1024 + kt * 64 + lg * 16)) ^ (unsigned)((m & 7) << 4);
                a[mf] = *(const short8*)(lds + off);
            }
#pragma unroll
            for (int nf = 0; nf < 8; ++nf) {
                int n = wn * 128 + nf * 16 + lr;
                b[nf] = *(const short8*)(lds + LDS_W + (((unsigned)(n * 64 + lg * 16)) ^ (unsigned)((n & 7) << 4)));
            }
#pragma unroll
            for (int mf = 0; mf < 4; ++mf)
#pragma unroll
                for (int nf = 0; nf < 8; ++nf)
                    acc[mf][nf] = __builtin_amdgcn_mfma_f32_16x16x32_bf16(a[mf], b[nf], acc[mf][nf], 0, 0, 0);
        }
        __syncthreads();           // last-iter reads done
        epilogueToH(acc, bias);    // in-place overwrite of H
        __syncthreads();
    }

    // ---------------- Layer 4: h3 @ w4^T (N=16 padded, 10 real) ----------------
    {
        // stage w4 panel (16 KiB) into W region
        const unsigned char* src = ws + W4_OFF + wave * 2048 + lane * 16;
        unsigned char* dst = lds + LDS_W + wave * 2048;
#pragma unroll
        for (int i = 0; i < 2; ++i) {
            __builtin_amdgcn_global_load_lds(
                (const __attribute__((address_space(1))) void*)(src + i * 1024),
                (__attribute__((address_space(3))) void*)(dst + i * 1024),
                16, 0, 0);
        }
        __syncthreads();

        f32x4 acc = (f32x4){0.f, 0.f, 0.f, 0.f};
        const int m = wave * 16 + lr;          // each wave: 16 rows
#pragma unroll
        for (int ks = 0; ks < NK2; ++ks) {
            unsigned aoff = ((unsigned)(m * 1024 + ks * 64 + lg * 16)) ^ (unsigned)((m & 7) << 4);
            short8 a = *(const short8*)(lds + aoff);
            unsigned boff = ((unsigned)(lr * 1024 + ks * 64 + lg * 16)) ^ (unsigned)((lr & 7) << 4);
            short8 b = *(const short8*)(lds + LDS_W + boff);
            acc = __builtin_amdgcn_mfma_f32_16x16x32_bf16(a, b, acc, 0, 0, 0);
        }

        int o = lr;                            // output col = lane&15
        if (o < 10) {
            float bv = b4[o];
#pragma unroll
            for (int r = 0; r < 4; ++r) {
                int row = row_base + wave * 16 + lg * 4 + r;
                out[(size_t)row * 10 + o] = acc[r] + bv;
            }
        }
    }
}

extern "C" void kernel_launch(void* const* d_in, const int* in_sizes, int n_in,
                              void* d_out, int out_size, void* d_ws, size_t ws_size,
                              hipStream_t stream) {
    const float* x  = (const float*)d_in[0];
    const float* w1 = (const float*)d_in[1];
    const float* b1 = (const float*)d_in[2];
    const float* w2 = (const float*)d_in[3];
    const float* b2 = (const float*)d_in[4];
    const float* w3 = (const float*)d_in[5];
    const float* b3 = (const float*)d_in[6];
    const float* w4 = (const float*)d_in[7];
    const float* b4 = (const float*)d_in[8];
    float* out = (float*)d_out;
    unsigned char* ws = (unsigned char*)d_ws;

    if (ws_size < (size_t)WS_BYTES) return;   // loud failure instead of corruption

    const int B = in_sizes[0] / K1;           // 65536
    const int nblk = B / BM;                  // 512

    (void)hipFuncSetAttribute((const void*)fused_mlp,
                              hipFuncAttributeMaxDynamicSharedMemorySize, LDS_TOTAL);

    const int prep_total = HID * K1P + 2 * HID * HID + 16 * HID;   // 942080
    prep_weights<<<(prep_total + 255) / 256, 256, 0, stream>>>(w1, w2, w3, w4, ws);
    fused_mlp<<<nblk, THREADS, LDS_TOTAL, stream>>>(x, ws, b1, b2, b3, b4, out);
}